// Round 1
// baseline (22084.784 us; speedup 1.0000x reference)
//
#include <hip/hip_runtime.h>
#include <stdint.h>

// LSTM, 2 layers, T=2048 B=32 I=H=256. Dtype-adaptive: probes at runtime
// whether float arrays are bf16 or fp32 (reference declares fp32; harness may
// or may not bf16-ify). Compute is bf16-MFMA with fp32 state either way.
//
// Persistent kernel, 32 WGs (16/layer), weights pinned in LDS
// ([W_ih | W_hh] fused -> K=512), cross-WG h exchange via device-coherent
// AGENT-scope atomic loads/stores (pipelined sc0/sc1 global ops — NOT RMW
// atomics; RMW reads serialized at the coherence point and dominated the
// previous version's 11 us/step) in d_ws, 2-deep slot ring with flag
// back-pressure. Layer 1 pipelined one step behind layer 0. h_ex zeroed and
// flags set to -1 on stream each launch (graph-capturable memsets).

#define TT 2048
#define BB 32
#define HH 256
#define NG 16            // workgroups per layer
#define UPW 16           // hidden units per WG
#define ROWS 64          // 4 gates * UPW weight rows per WG
#define KP 520           // padded K row length in bf16 elems (512 + 8)
#define NSLOT 2          // h-exchange ring depth

#define OFF_W    0                       // [ROWS][KP] bf16  = 66560 B
#define OFF_HX   66560                   // [BB][KP]  bf16   = 33280 B
#define OFF_G    99840                   // [ROWS][33] f32   =  8448 B
#define OFF_HOB  108288                  // [BB][UPW] bf16   =  1024 B
#define OFF_COB  109312                  // [BB][UPW] bf16   =  1024 B
#define OFF_HOF  110336                  // [BB][UPW] f32    =  2048 B
#define OFF_COF  112384                  // [BB][UPW] f32    =  2048 B
#define LDS_BYTES 114432

#define WS_HEX_DW   (2 * NSLOT * BB * (HH / 2))   // 16384 dwords = 64 KiB
#define WS_FLAG_OFF (WS_HEX_DW * 4)               // byte offset of flags
#define WS_FLAG_BYTES (2 * NSLOT * NG * 4)        // 256 B

typedef __attribute__((ext_vector_type(8))) short bf16x8;
typedef __attribute__((ext_vector_type(4))) float f32x4;
typedef unsigned short u16;
typedef unsigned int u32;

__device__ __forceinline__ float bf2f(u16 u) {
    u32 x = ((u32)u) << 16;
    return __builtin_bit_cast(float, x);
}
__device__ __forceinline__ u16 f2bf(float f) {
    u32 x = __builtin_bit_cast(u32, f);
    x += 0x7fffu + ((x >> 16) & 1u);   // RNE
    return (u16)(x >> 16);
}
__device__ __forceinline__ u32 pack2(float lo, float hi) {
    return (u32)f2bf(lo) | ((u32)f2bf(hi) << 16);
}
__device__ __forceinline__ float bcf(u32 v) { return __builtin_bit_cast(float, v); }
// 8 fp32 (two uint4) -> 8 bf16 (one uint4)
__device__ __forceinline__ uint4 cvt8(uint4 a, uint4 b) {
    uint4 r;
    r.x = pack2(bcf(a.x), bcf(a.y));
    r.y = pack2(bcf(a.z), bcf(a.w));
    r.z = pack2(bcf(b.x), bcf(b.y));
    r.w = pack2(bcf(b.z), bcf(b.w));
    return r;
}

// ---- device-coherent (agent-scope) pipelined load/store: global_* sc0 sc1 ----
__device__ __forceinline__ u32 cload(const u32* p) {
    return __hip_atomic_load(p, __ATOMIC_RELAXED, __HIP_MEMORY_SCOPE_AGENT);
}
__device__ __forceinline__ void cstore(u32* p, u32 v) {
    __hip_atomic_store(p, v, __ATOMIC_RELAXED, __HIP_MEMORY_SCOPE_AGENT);
}

__device__ __forceinline__ void poll_ge(int* f, int tag) {
    int it = 0;
    while (__hip_atomic_load(f, __ATOMIC_RELAXED, __HIP_MEMORY_SCOPE_AGENT) < tag) {
        __builtin_amdgcn_s_sleep(2);
        if (++it > 2000000) break;           // anti-hang valve (~1 s)
    }
}

__global__ __launch_bounds__(256) void lstm_kernel(
    const u16* __restrict__ x, const int* __restrict__ lengths,
    const u16* __restrict__ h0, const u16* __restrict__ c0,
    const u16* __restrict__ Wih0, const u16* __restrict__ Whh0, const u16* __restrict__ b0,
    const u16* __restrict__ Wih1, const u16* __restrict__ Whh1, const u16* __restrict__ b1,
    u16* __restrict__ out, u32* __restrict__ ws)
{
    extern __shared__ char lds[];
    const int tid = threadIdx.x;
    const int wg = blockIdx.x;          // 0..31
    const int layer = wg >> 4;
    const int g = wg & 15;
    const int ubase = g * UPW;

    // ---- dtype probe: bf16 data -> exponent fields of even u16s are ~always
    // in [96,144]; fp32 data -> even u16s are low mantissa halves, uniform ----
    if (tid == 0) *(volatile int*)lds = 0;
    __syncthreads();
    {
        int e = (((const u16*)x)[(u32)tid * 64] >> 7) & 0xff;
        if (e >= 96 && e <= 144) atomicAdd((int*)lds, 1);
    }
    __syncthreads();
    const bool bfm = (*(volatile int*)lds >= 150);
    __syncthreads();

    const u16* Wih = layer ? Wih1 : Wih0;
    const u16* Whh = layer ? Whh1 : Whh0;
    const u16* bias = layer ? b1 : b0;

    u32* h_ex = ws;                                  // [2][NSLOT][BB][128] u32
    int* flags = (int*)(ws + WS_HEX_DW);             // [2][NSLOT][NG]

    // ---- load fused [W_ih | W_hh] slice into LDS (bf16, converting if fp32) ----
    for (int c = tid; c < ROWS * 64; c += 256) {
        int r = c >> 6, part = c & 63;
        int R = (r & 3) * 256 + ubase + (r >> 2);    // gate*256 + unit
        uint4 v;
        if (bfm) {
            v = (part < 32) ? ((const uint4*)Wih)[R * 32 + part]
                            : ((const uint4*)Whh)[R * 32 + (part - 32)];
        } else {
            const uint4* s = (part < 32) ? ((const uint4*)Wih) + R * 64 + part * 2
                                         : ((const uint4*)Whh) + R * 64 + (part - 32) * 2;
            v = cvt8(s[0], s[1]);
        }
        *(uint4*)(lds + OFF_W + r * (KP * 2) + part * 16) = v;
    }

    // ---- per-thread recurrent state: 2 (batch, unit) pairs ----
    const int b = tid & 31;
    const int u0 = tid >> 5;            // 0..7
    // lengths: int64 per reference, int32 possible. values in [1,2048] so an
    // int32 array never has 0 at index 1; int64 always does (high word).
    const bool len64 = (lengths[1] == 0);
    const int lenb = len64 ? lengths[2 * b] : lengths[b];
    float cr[2], hp[2], bi[2][4];
#pragma unroll
    for (int pp = 0; pp < 2; ++pp) {
        int ug = ubase + u0 + 8 * pp;
        int idx = layer * BB * HH + b * HH + ug;
        cr[pp] = bfm ? bf2f(c0[idx]) : ((const float*)c0)[idx];
        hp[pp] = bfm ? bf2f(h0[idx]) : ((const float*)h0)[idx];
#pragma unroll
        for (int gate = 0; gate < 4; ++gate)
            bi[pp][gate] = bfm ? bf2f(bias[gate * 256 + ug])
                               : ((const float*)bias)[gate * 256 + ug];
    }

    // x prefetch (layer 0): bf16 slab = 1024 uint4; fp32 slab = 2048 uint4
    uint4 xr[8];
    if (layer == 0) {
        if (bfm) {
#pragma unroll
            for (int j = 0; j < 4; ++j) xr[j] = ((const uint4*)x)[tid + j * 256];
        } else {
#pragma unroll
            for (int j = 0; j < 4; ++j) {
                int e = tid + j * 256;
                xr[2 * j]     = ((const uint4*)x)[2 * e];
                xr[2 * j + 1] = ((const uint4*)x)[2 * e + 1];
            }
        }
    }

    const int lane = tid & 63;
    const int wave = tid >> 6;
    const int lq = lane >> 4;
    const int lm = lane & 15;

    __syncthreads();   // weights visible

    for (int t = 0; t < TT; ++t) {
        const int slot = t & (NSLOT - 1);
        const int pslot = (t - 1) & (NSLOT - 1);

        // ---- producer waits (wave0) + ring back-pressure (wave1) ----
        if (layer == 0) {
            if (wave == 0 && lane < 16 && t > 0)
                poll_ge(&flags[(0 * NSLOT + pslot) * NG + lane], t);
            if (wave == 1 && lane < 16 && t >= NSLOT)
                poll_ge(&flags[(1 * NSLOT + slot) * NG + lane], t - NSLOT + 1);
        } else {
            if (wave == 0 && lane < 16)
                poll_ge(&flags[(0 * NSLOT + slot) * NG + lane], t + 1);
            if (wave == 1 && lane < 16 && t > 0)
                poll_ge(&flags[(1 * NSLOT + pslot) * NG + lane], t);
        }
        asm volatile("" ::: "memory");
        __syncthreads();

        // ---- stage hx = [x_t or h0_t | h_prev] into LDS ----
        if (layer == 0) {
#pragma unroll
            for (int j = 0; j < 4; ++j) {
                int e = tid + j * 256;
                uint4 v = bfm ? xr[j] : cvt8(xr[2 * j], xr[2 * j + 1]);
                *(uint4*)(lds + OFF_HX + (e >> 5) * (KP * 2) + (e & 31) * 16) = v;
            }
            if (t == 0) {
#pragma unroll
                for (int j = 0; j < 16; ++j) {
                    int d = tid + j * 256;
                    u32 v = bfm ? ((const u32*)h0)[d]
                                : pack2(((const float*)h0)[2 * d], ((const float*)h0)[2 * d + 1]);
                    *(u32*)(lds + OFF_HX + (d >> 7) * (KP * 2) + 512 + (d & 127) * 4) = v;
                }
            } else {
                u32* src = h_ex + (0 * NSLOT + pslot) * (BB * 128);
#pragma unroll
                for (int j = 0; j < 16; ++j) {
                    int d = tid + j * 256;
                    u32 v = cload(src + d);            // coherent pipelined read
                    *(u32*)(lds + OFF_HX + (d >> 7) * (KP * 2) + 512 + (d & 127) * 4) = v;
                }
            }
            if (t + 1 < TT) {
                if (bfm) {
#pragma unroll
                    for (int j = 0; j < 4; ++j)
                        xr[j] = ((const uint4*)x)[(t + 1) * 1024 + tid + j * 256];
                } else {
#pragma unroll
                    for (int j = 0; j < 4; ++j) {
                        int e = tid + j * 256;
                        xr[2 * j]     = ((const uint4*)x)[(t + 1) * 2048 + 2 * e];
                        xr[2 * j + 1] = ((const uint4*)x)[(t + 1) * 2048 + 2 * e + 1];
                    }
                }
            }
        } else {
            u32* src0 = h_ex + (0 * NSLOT + slot) * (BB * 128);
#pragma unroll
            for (int j = 0; j < 16; ++j) {      // K[0:256) = h0_t from layer 0
                int d = tid + j * 256;
                u32 v = cload(src0 + d);
                *(u32*)(lds + OFF_HX + (d >> 7) * (KP * 2) + (d & 127) * 4) = v;
            }
            if (t == 0) {
#pragma unroll
                for (int j = 0; j < 16; ++j) {
                    int d = tid + j * 256;
                    u32 v = bfm ? ((const u32*)h0)[4096 + d]
                                : pack2(((const float*)h0)[8192 + 2 * d],
                                        ((const float*)h0)[8192 + 2 * d + 1]);
                    *(u32*)(lds + OFF_HX + (d >> 7) * (KP * 2) + 512 + (d & 127) * 4) = v;
                }
            } else {
                u32* src1 = h_ex + (1 * NSLOT + pslot) * (BB * 128);
#pragma unroll
                for (int j = 0; j < 16; ++j) {
                    int d = tid + j * 256;
                    u32 v = cload(src1 + d);
                    *(u32*)(lds + OFF_HX + (d >> 7) * (KP * 2) + 512 + (d & 127) * 4) = v;
                }
            }
        }
        __syncthreads();

        // ---- MFMA: gates[batch 32][row 64] = hx[32,512] @ W[64,512]^T ----
        {
            f32x4 acc0 = {0.f, 0.f, 0.f, 0.f}, acc1 = {0.f, 0.f, 0.f, 0.f};
            const int n = wave * 16 + lm;
            const char* wrow  = lds + OFF_W  + n * (KP * 2) + lq * 16;
            const char* arow0 = lds + OFF_HX + lm * (KP * 2) + lq * 16;
            const char* arow1 = lds + OFF_HX + (16 + lm) * (KP * 2) + lq * 16;
#pragma unroll
            for (int ks = 0; ks < 16; ++ks) {
                bf16x8 bf = *(const bf16x8*)(wrow + ks * 64);
                bf16x8 a0 = *(const bf16x8*)(arow0 + ks * 64);
                bf16x8 a1 = *(const bf16x8*)(arow1 + ks * 64);
                acc0 = __builtin_amdgcn_mfma_f32_16x16x32_bf16(a0, bf, acc0, 0, 0, 0);
                acc1 = __builtin_amdgcn_mfma_f32_16x16x32_bf16(a1, bf, acc1, 0, 0, 0);
            }
            float* gcol = (float*)(lds + OFF_G) + n * 33;   // gates[row][batch]
#pragma unroll
            for (int r = 0; r < 4; ++r) {
                gcol[lq * 4 + r]      = acc0[r];
                gcol[16 + lq * 4 + r] = acc1[r];
            }
        }
        __syncthreads();

        // ---- pointwise LSTM cell update (fp32) ----
        {
            const float* gb = (const float*)(lds + OFF_G);
            u16* hob = (u16*)(lds + OFF_HOB);
            u16* cob = (u16*)(lds + OFF_COB);
#pragma unroll
            for (int pp = 0; pp < 2; ++pp) {
                int u = u0 + 8 * pp;
                float gi = gb[(4 * u + 0) * 33 + b] + bi[pp][0];
                float gf = gb[(4 * u + 1) * 33 + b] + bi[pp][1];
                float gg = gb[(4 * u + 2) * 33 + b] + bi[pp][2];
                float go = gb[(4 * u + 3) * 33 + b] + bi[pp][3];
                float si = 1.f / (1.f + __expf(-gi));
                float sf = 1.f / (1.f + __expf(-gf));
                float so = 1.f / (1.f + __expf(-go));
                float cn = sf * cr[pp] + si * tanhf(gg);
                float hn = so * tanhf(cn);
                if (t >= lenb) { cn = cr[pp]; hn = hp[pp]; }
                cr[pp] = cn; hp[pp] = hn;
                hob[b * UPW + u] = f2bf(hn);
                cob[b * UPW + u] = f2bf(cn);
                if (!bfm) {
                    ((float*)(lds + OFF_HOF))[b * UPW + u] = hn;
                    ((float*)(lds + OFF_COF))[b * UPW + u] = cn;
                }
            }
        }
        __syncthreads();

        // ---- publish h slice (+ layer-1 writes hs/cs outputs) ----
        {
            u32 hv = ((const u32*)(lds + OFF_HOB))[tid];
            int bb2 = tid >> 3, u2 = tid & 7;
            u32* dst = h_ex + (layer * NSLOT + slot) * (BB * 128) + bb2 * 128 + g * 8 + u2;
            cstore(dst, hv);                            // coherent pipelined write
            if (layer == 1) {
                if (bfm) {
                    u32 cv = ((const u32*)(lds + OFF_COB))[tid];
                    u32* outu = (u32*)out;
                    outu[t * 4096 + bb2 * 128 + g * 8 + u2] = hv;
                    outu[(TT * BB * HH / 2) + t * 4096 + bb2 * 128 + g * 8 + u2] = cv;
                } else {
                    float2 h2 = ((const float2*)(lds + OFF_HOF))[tid];
                    float2 c2 = ((const float2*)(lds + OFF_COF))[tid];
                    float2* outf2 = (float2*)out;
                    outf2[t * 4096 + bb2 * 128 + g * 8 + u2] = h2;
                    outf2[(TT * BB * HH / 2) + t * 4096 + bb2 * 128 + g * 8 + u2] = c2;
                }
            }
        }
        asm volatile("s_waitcnt vmcnt(0)" ::: "memory");
        __syncthreads();
        if (tid == 0)
            __hip_atomic_store(&flags[(layer * NSLOT + slot) * NG + g], t + 1,
                               __ATOMIC_RELAXED, __HIP_MEMORY_SCOPE_AGENT);
    }

    // ---- finals: h_T, c_T (post-mask, held in regs) ----
    {
        const int base = 2 * TT * BB * HH;
#pragma unroll
        for (int pp = 0; pp < 2; ++pp) {
            int ug = ubase + u0 + 8 * pp;
            if (bfm) {
                out[base + layer * BB * HH + b * HH + ug] = f2bf(hp[pp]);
                out[base + 2 * BB * HH + layer * BB * HH + b * HH + ug] = f2bf(cr[pp]);
            } else {
                float* outf = (float*)out;
                outf[base + layer * BB * HH + b * HH + ug] = hp[pp];
                outf[base + 2 * BB * HH + layer * BB * HH + b * HH + ug] = cr[pp];
            }
        }
    }
}

extern "C" void kernel_launch(void* const* d_in, const int* in_sizes, int n_in,
                              void* d_out, int out_size, void* d_ws, size_t ws_size,
                              hipStream_t stream) {
    (void)in_sizes; (void)n_in; (void)out_size; (void)ws_size;
    // Deterministic ws init on EVERY call: h_ex = 0 (finite), flags = -1.
    hipMemsetAsync(d_ws, 0, WS_FLAG_OFF, stream);
    hipMemsetAsync((char*)d_ws + WS_FLAG_OFF, 0xFF, WS_FLAG_BYTES, stream);
    hipFuncSetAttribute((const void*)lstm_kernel,
                        hipFuncAttributeMaxDynamicSharedMemorySize, LDS_BYTES);
    lstm_kernel<<<dim3(32), dim3(256), LDS_BYTES, stream>>>(
        (const u16*)d_in[0], (const int*)d_in[1],
        (const u16*)d_in[2], (const u16*)d_in[3],
        (const u16*)d_in[4], (const u16*)d_in[5], (const u16*)d_in[6],
        (const u16*)d_in[7], (const u16*)d_in[8], (const u16*)d_in[9],
        (u16*)d_out, (u32*)d_ws);
}